// Round 5
// baseline (5446.223 us; speedup 1.0000x reference)
//
#include <hip/hip_runtime.h>
#include <stdint.h>

// Problem constants
#define SEQ   2048
#define DE    256
#define DXX   64
#define DIN   320      // DE + DX
#define HH    256      // hidden per direction
#define G4    1024     // 4*HH
#define NT    64       // tags

// Workspace layout (float32 slot indices)
static constexpr size_t OFF_GX = 0;
static constexpr size_t OFF_H  = OFF_GX + (size_t)2 * SEQ * G4;        // 4194304
static constexpr size_t HSTR   = (size_t)SEQ * HH;                     // 524288
static constexpr size_t OFF_SL = OFF_H + 2 * HSTR;                     // 5242880 (8B-aligned)
static constexpr size_t OFF_FE = OFF_SL + 2048;                        // 5244928
static constexpr size_t OFF_BP = OFF_FE + (size_t)SEQ * NT;            // 5376000
static constexpr size_t WS_NEEDED_BYTES = OFF_BP * 4 + (size_t)SEQ * NT; // ~21.6 MB

// LDS-visibility-only barrier: drains lgkmcnt (LDS) but leaves global
// loads/stores in flight (vmcnt NOT drained). __syncthreads() would emit
// s_waitcnt vmcnt(0) before s_barrier, serializing store-acks and prefetch
// loads into every step. Safe wherever cross-wave deps flow through LDS
// only (HK-standard pattern).
__device__ __forceinline__ void bar_lds() {
  asm volatile("s_waitcnt lgkmcnt(0)\n\ts_barrier" ::: "memory");
}

// ---------------------------------------------------------------------------
// K0: reset both slot buffers to (h=0, tag=0). Buffer 0 == h_{-1} for t=0.
// ---------------------------------------------------------------------------
__global__ __launch_bounds__(256) void k_init(unsigned long long* __restrict__ slot) {
  const int tid = threadIdx.x;
  #pragma unroll
  for (int b = 0; b < 4; ++b) slot[b * 256 + tid] = 0ull;   // 2 dirs x 2 bufs
}

// ---------------------------------------------------------------------------
// K1: fused gather + gx = x @ w_ih.T + (b_ih + b_hh), both directions.
// grid (SEQ/32, G4/256, 2), block 512.
// ---------------------------------------------------------------------------
__global__ __launch_bounds__(512) void k_gx(
    const int* __restrict__ sent, const int* __restrict__ extra,
    const float* __restrict__ emb, const float* __restrict__ xemb,
    const float* __restrict__ wf, const float* __restrict__ wb,
    const float* __restrict__ bif, const float* __restrict__ bhf,
    const float* __restrict__ bib, const float* __restrict__ bhb,
    float* __restrict__ GX) {
  __shared__ __align__(16) float xs[32][36];    // [kk][s_local]
  __shared__ __align__(16) float wl[32][260];   // [kk][r_local]
  const int tid = threadIdx.x;
  const int s0 = blockIdx.x * 32, r0 = blockIdx.y * 256, dir = blockIdx.z;
  const float* W = dir ? wb : wf;
  const int tids = tid & 7;        // s-group (4 s each)
  const int tidr = tid >> 3;       // r-group (4 r each), 0..63
  float acc[4][4];
  #pragma unroll
  for (int a = 0; a < 4; ++a)
    #pragma unroll
    for (int b = 0; b < 4; ++b) acc[a][b] = 0.f;

  for (int kc = 0; kc < 10; ++kc) {
    const int k0 = kc * 32;
    __syncthreads();
    for (int e = tid; e < 1024; e += 512) {     // x tile (fused gather)
      int kk = e & 31, sl = e >> 5;
      int s = s0 + sl;
      int src = dir ? (SEQ - 1 - s) : s;
      int k = k0 + kk;
      float v;
      if (k < DE) v = emb[(size_t)sent[src] * DE + k];
      else        v = xemb[(size_t)extra[src] * DXX + (k - DE)];
      xs[kk][sl] = v;
    }
    for (int e = tid; e < 8192; e += 512) {     // w tile
      int kk = e & 31, rl = e >> 5;
      wl[kk][rl] = W[(size_t)(r0 + rl) * DIN + k0 + kk];
    }
    __syncthreads();
    #pragma unroll
    for (int kk = 0; kk < 32; ++kk) {
      float4 xv = *(const float4*)&xs[kk][4 * tids];
      float4 wv = *(const float4*)&wl[kk][4 * tidr];
      acc[0][0] += xv.x * wv.x; acc[0][1] += xv.x * wv.y; acc[0][2] += xv.x * wv.z; acc[0][3] += xv.x * wv.w;
      acc[1][0] += xv.y * wv.x; acc[1][1] += xv.y * wv.y; acc[1][2] += xv.y * wv.z; acc[1][3] += xv.y * wv.w;
      acc[2][0] += xv.z * wv.x; acc[2][1] += xv.z * wv.y; acc[2][2] += xv.z * wv.z; acc[2][3] += xv.z * wv.w;
      acc[3][0] += xv.w * wv.x; acc[3][1] += xv.w * wv.y; acc[3][2] += xv.w * wv.z; acc[3][3] += xv.w * wv.w;
    }
  }
  const float* BI = dir ? bib : bif;
  const float* BH = dir ? bhb : bhf;
  float4 b1 = *(const float4*)&BI[r0 + 4 * tidr];
  float4 b2 = *(const float4*)&BH[r0 + 4 * tidr];
  float bx = b1.x + b2.x, by = b1.y + b2.y, bz = b1.z + b2.z, bw = b1.w + b2.w;
  #pragma unroll
  for (int ss = 0; ss < 4; ++ss) {
    int s = s0 + 4 * tids + ss;
    float4 o;
    o.x = acc[ss][0] + bx; o.y = acc[ss][1] + by; o.z = acc[ss][2] + bz; o.w = acc[ss][3] + bw;
    *(float4*)&GX[((size_t)dir * SEQ + s) * G4 + r0 + 4 * tidr] = o;
  }
}

// ---------------------------------------------------------------------------
// K2: persistent BiLSTM, 16-way partition + DOUBLE-BUFFERED tagged-slot
// exchange. grid 32 (= 2 dirs x 16 parts), block 256.
//
// Round-5 restructure (theory: R2-R4 micro-opts all flat because the step
// was gated by WRITER-side serialization none of them touched):
//  (A) in-order vmcnt was draining the publish store's agent-scope ack into
//      the publisher wave's next poll wait (~300-600cy/step), and
//      __syncthreads' vmcnt(0) drain at BOTH barriers serialized every
//      in-flight global op each step. Fix:
//       - bar_lds(): s_waitcnt lgkmcnt(0) + s_barrier only. All cross-wave
//         deps inside the loop flow through LDS (hl, psum); global ops
//         (publish, Hd, gxv, polls) are protocol-tolerant of delay.
//       - role split: wave 3 (tid>=192) does combine+gates+publish (+gxv
//         prefetch); waves 0-2 poll + matvec only. Polling waves now have
//         ZERO stores in their vmcnt queue; wave 3's only vmcnt wait (gxv
//         at combine) sits bar1+matvec+bar2 (~500cy) after its publish, so
//         the ack is long retired. Gates/publish also overlap the other
//         waves' next-step polls.
//  (B) poll coverage: lanes 0-191 poll slot tid; lanes 0-63 also poll slot
//      192+tid (two independent loads per poll iteration). Own-block slots
//      skipped; owners write their h into hl directly (between bar2(t) and
//      bar1(t+1) - single-buffer safe since matvec(t) LDS reads drained at
//      raw bar2).
//  Race safety of 2 lgkm-only barriers/step: hl poll-writes(t+1) happen
//  after that wave passed bar2(t) (so all matvec(t) reads incl. wave 3's
//  retired); psum(t+1) writes happen after bar1(t+1), which requires wave
//  3's arrival, which is after its combine(t) psum reads. No deadlock:
//  lockstep chain has no cycle; poll budget is a pure failsafe.
//  FP trees identical to R2/R4 (gxv + ((p0+p1)+(p2+p3)); same sigmoid/tanh
//  exprs) -> h trajectory bit-exact -> tags unchanged.
//
// Exchange protocol (unchanged): reader of step t polls buf[t&1] slot until
// tag==t (data rides in the same 8B atom). Publisher writes (h_t, t+1) into
// buf[(t+1)&1]; max skew = 1 step => equality-poll can never miss.
// ---------------------------------------------------------------------------
__global__ __launch_bounds__(256, 1) void k_lstm16(
    const float* __restrict__ whf, const float* __restrict__ whb,
    const float* __restrict__ GX, float* __restrict__ H,
    unsigned long long* __restrict__ slot) {
  const int dir = blockIdx.x >> 4;
  const int p   = blockIdx.x & 15;
  const int tid = threadIdx.x;
  const int rr  = tid >> 2;            // local matvec row 0..63
  const int q   = tid & 3;             // k-quarter
  const int gq  = rr >> 4;             // gate of local row
  const int joq = rr & 15;             // local elem of local row
  const int rowQ = (gq << 8) | (p << 4) | joq;      // matvec row

  const float4* w4g =
      (const float4*)((dir ? whb : whf) + (size_t)rowQ * HH) + q * 16;
  float4 w[16];
  #pragma unroll
  for (int i = 0; i < 16; ++i) w[i] = w4g[i];
  #pragma unroll
  for (int i = 0; i < 16; ++i)
    asm volatile("" : "+v"(w[i].x), "+v"(w[i].y), "+v"(w[i].z), "+v"(w[i].w));

  const bool isw3 = (tid >= 192);      // combine/gates/publish wave
  const int cc = tid & 63;             // wave-3 combine row id (== tid-192)
  const int rowC = ((cc >> 4) << 8) | (p << 4) | (cc & 15);
  const float* gxc = GX + (size_t)dir * SEQ * G4 + rowC;  // used by wave 3
  float* Hd = H + (size_t)dir * HSTR;
  unsigned long long* sl = slot + dir * 512;   // [buf=2][256]

  // bank-staggered h broadcast: element e at [e>>6][e&63] (272B quarter
  // stride -> 4 disjoint bank quads; 0 conflicts measured since R1).
  __shared__ __align__(16) float hl[4][68];
  __shared__ float psum[256];
  float c = 0.f;                       // valid in wave-3 lanes cc<16
  int budget = 1 << 18;                // pure failsafe

  // poll assignment (waves 0-2 cover all 256 slots; own 16 skipped)
  const int s1 = tid;                  // valid tid<192
  const int s2 = 192 + tid;            // valid tid<64
  const bool need1 = !isw3 && ((s1 >> 4) != p);
  const bool need2 = (tid < 64) && ((s2 >> 4) != p);

  if (isw3 && cc < 16) {               // h_{-1}=0 for own elements
    int jj = (p << 4) | cc;
    hl[jj >> 6][jj & 63] = 0.f;        // ordered before matvec(0) by bar1(0)
  }

  for (int t = 0; t < SEQ; ++t) {
    float gxv = 0.f;
    if (isw3) gxv = gxc[(size_t)t * G4];   // prefetch; consumed after bar2
    if (need1 | need2) {
      const unsigned tw = (unsigned)t;
      unsigned long long* sp1 = &sl[(t & 1) * 256 + s1];
      unsigned long long* sp2 = &sl[(t & 1) * 256 + s2];
      bool d1 = !need1, d2 = !need2;
      do {
        if (!d1) {
          unsigned long long v = __hip_atomic_load(sp1, __ATOMIC_RELAXED, __HIP_MEMORY_SCOPE_AGENT);
          if ((unsigned)(v >> 32) == tw) {
            union { unsigned u; float f; } cv; cv.u = (unsigned)v;
            hl[s1 >> 6][s1 & 63] = cv.f; d1 = true;
          }
        }
        if (!d2) {
          unsigned long long v = __hip_atomic_load(sp2, __ATOMIC_RELAXED, __HIP_MEMORY_SCOPE_AGENT);
          if ((unsigned)(v >> 32) == tw) {
            union { unsigned u; float f; } cv; cv.u = (unsigned)v;
            hl[s2 >> 6][s2 & 63] = cv.f; d2 = true;
          }
        }
      } while (!(d1 && d2) && --budget > 0);
    }
    bar_lds();                         // bar1: hl ready (lgkm-only)
    const float4* h4 = (const float4*)(hl[q]);
    float a0 = 0.f, a1 = 0.f, a2 = 0.f, a3 = 0.f;
    #pragma unroll
    for (int i = 0; i < 16; ++i) {
      float4 wv = w[i];
      float4 hv = h4[i];
      a0 += wv.x * hv.x; a1 += wv.y * hv.y; a2 += wv.z * hv.z; a3 += wv.w * hv.w;
    }
    psum[tid] = (a0 + a1) + (a2 + a3);
    bar_lds();                         // bar2: psum ready (lgkm-only)
    if (isw3) {  // wave 3: combine + gate-parallel nonlinearity + publish
      float s = gxv + ((psum[4 * cc] + psum[4 * cc + 1]) +
                       (psum[4 * cc + 2] + psum[4 * cc + 3]));
      const int gg_ = cc >> 4;         // gate (0=i,1=f,2=g,3=o)
      const int ee  = cc & 15;         // element
      float sig = 1.f / (1.f + expf(-s));
      float th  = tanhf(s);
      float gated = (gg_ == 2) ? th : sig;
      float fg = __shfl(gated, 16 + ee);
      float gv = __shfl(gated, 32 + ee);
      float og = __shfl(gated, 48 + ee);
      if (cc < 16) {   // owner lane: state update + publish
        c = fg * c + gated * gv;       // gated == sigmoid(i-row)
        float h = og * tanhf(c);
        int jj = (p << 4) | cc;
        union { float f; unsigned u; } hu; hu.f = h;
        unsigned long long pk =
            ((unsigned long long)(unsigned)(t + 1) << 32) | hu.u;
        __hip_atomic_store(&sl[((t + 1) & 1) * 256 + jj], pk, __ATOMIC_RELAXED,
                           __HIP_MEMORY_SCOPE_AGENT);   // publish FIRST
        hl[jj >> 6][jj & 63] = h;      // own-entry LDS shortcut (pre-bar1(t+1))
        Hd[(size_t)t * HH + jj] = h;   // plain store for k_feats
      }
    }
  }
}

// ---------------------------------------------------------------------------
// K3: feats = [hf, hb_rev] @ fc_w.T + fc_b.  grid SEQ/16, block 256.
// ---------------------------------------------------------------------------
__global__ __launch_bounds__(256) void k_feats(
    const float* __restrict__ HF, const float* __restrict__ HB,
    const float* __restrict__ fcw, const float* __restrict__ fcb,
    float* __restrict__ FE) {
  __shared__ float hlds[16][512];
  __shared__ float wl[64][65];
  const int tid = threadIdx.x;
  const int s0 = blockIdx.x * 16;
  for (int e = tid; e < 16 * 512; e += 256) {
    int sl = e >> 9, k = e & 511;
    float v = (k < HH) ? HF[(size_t)(s0 + sl) * HH + k]
                       : HB[(size_t)(SEQ - 1 - (s0 + sl)) * HH + (k - HH)];
    hlds[sl][k] = v;
  }
  const int j = tid & 63, sg = tid >> 6;
  float acc[4];
  #pragma unroll
  for (int q = 0; q < 4; ++q) acc[q] = fcb[j];
  for (int kc = 0; kc < 8; ++kc) {
    __syncthreads();
    for (int e = tid; e < 4096; e += 256) {
      int kk = e & 63, jj = e >> 6;
      wl[kk][jj] = fcw[(size_t)jj * 512 + kc * 64 + kk];
    }
    __syncthreads();
    #pragma unroll 8
    for (int kk = 0; kk < 64; ++kk) {
      float wv = wl[kk][j];
      int kg = kc * 64 + kk;
      #pragma unroll
      for (int q = 0; q < 4; ++q) acc[q] += hlds[4 * sg + q][kg] * wv;
    }
  }
  #pragma unroll
  for (int q = 0; q < 4; ++q)
    FE[(size_t)(s0 + 4 * sg + q) * NT + j] = acc[q];
}

// ---------------------------------------------------------------------------
// K4: Viterbi. 1 block x 256 threads.
// Round-5: (a) feats row prefetched one iteration ahead; lgkm-only barriers
// keep the load in flight across the barrier (its s_waitcnt lands at next
// iter's first use, latency hidden under compute+bars). (b) backtrack via
// 32 x 64-step chunks staged into LDS (4KB each): the 2047-long dependent
// pointer chase becomes ds_reads (~40cy) instead of global L2 round trips
// (~300cy). Semantics unchanged: numpy-faithful strict-> first-max, bp
// computed on (sc[i]+tr[i][j])+fj exactly as before.
// ---------------------------------------------------------------------------
__global__ __launch_bounds__(256) void k_viterbi(
    const float* __restrict__ feats, const float* __restrict__ start,
    const float* __restrict__ endv, const float* __restrict__ trans,
    unsigned char* __restrict__ bp, int* __restrict__ out) {
  __shared__ float tr[64 * 64];
  __shared__ float sc[64];
  __shared__ float pval[4][64];
  __shared__ int pidx[4][64];
  __shared__ unsigned char bpl[64][64];   // backtrack chunk stage (4KB)
  const int tid = threadIdx.x;
  for (int e = tid; e < 4096; e += 256) tr[e] = trans[e];
  if (tid < 64) sc[tid] = start[tid] + feats[tid];
  __syncthreads();
  const int w = tid >> 6, j = tid & 63;
  float fj_cur = feats[1 * NT + j];          // prefetch row t=1
  for (int t = 1; t < SEQ; ++t) {
    float fj = fj_cur;
    if (t + 1 < SEQ) fj_cur = feats[(t + 1) * NT + j];   // prefetch next row
    float best = -3.0e38f; int bi = 0;
    const int ibase = w << 4;
    #pragma unroll
    for (int ii = 0; ii < 16; ++ii) {
      int i = ibase + ii;
      float v = (sc[i] + tr[(i << 6) | j]) + fj;
      if (v > best) { best = v; bi = i; }
    }
    pval[w][j] = best; pidx[w][j] = bi;
    bar_lds();
    if (w == 0) {
      float b = pval[0][j]; int x = pidx[0][j];
      if (pval[1][j] > b) { b = pval[1][j]; x = pidx[1][j]; }
      if (pval[2][j] > b) { b = pval[2][j]; x = pidx[2][j]; }
      if (pval[3][j] > b) { b = pval[3][j]; x = pidx[3][j]; }
      bp[t * NT + j] = (unsigned char)x;     // global store, fire-and-forget
      sc[j] = b;
    }
    bar_lds();
  }
  __syncthreads();   // full drain: bp stores committed before backtrack reads
  // final tag
  __shared__ int btag;
  if (tid == 0) {
    float best = -3.0e38f; int bt = 0;
    for (int i = 0; i < 64; ++i) {
      float v = sc[i] + endv[i];
      if (v > best) { best = v; bt = i; }
    }
    out[SEQ - 1] = bt;
    btag = bt;
  }
  __syncthreads();
  int tag = btag;    // live in lane 0; others just participate in staging
  for (int cchunk = 31; cchunk >= 0; --cchunk) {   // t in [64c, 64c+63]
    const int tbase = cchunk * 64;
    __syncthreads();                   // prev chase done before overwrite
    for (int wd = tid; wd < 1024; wd += 256)       // 64 rows x 16 u32
      ((unsigned int*)bpl)[wd] =
          ((const unsigned int*)bp)[tbase * 16 + wd];
    __syncthreads();                   // staged (drains the global loads)
    if (tid == 0) {
      #pragma unroll 4
      for (int k = 63; k >= 0; --k) {
        int t = tbase + k;
        if (t >= 1) {
          tag = bpl[k][tag];
          out[t - 1] = tag;
        }
      }
    }
  }
}

// ---------------------------------------------------------------------------
extern "C" void kernel_launch(void* const* d_in, const int* in_sizes, int n_in,
                              void* d_out, int out_size, void* d_ws, size_t ws_size,
                              hipStream_t stream) {
  // --- Defensive guards: any mismatch -> fail visibly (absmax), never fault.
  if (n_in < 19) return;
  if (in_sizes[0] != SEQ || in_sizes[1] != SEQ) return;              // sentence, extra
  if (in_sizes[2] != 1 || in_sizes[3] != 1) return;                  // b, e scalars
  if (in_sizes[4] != 100000 * DE) return;                            // emb
  if (in_sizes[5] != 1000 * DXX) return;                             // extra_emb
  if (in_sizes[6] != G4 * DIN || in_sizes[7] != G4 * HH) return;     // w_ih_f, w_hh_f
  if (in_sizes[8] != G4 || in_sizes[9] != G4) return;                // b_ih_f, b_hh_f
  if (in_sizes[10] != G4 * DIN || in_sizes[11] != G4 * HH) return;   // w_ih_b, w_hh_b
  if (in_sizes[14] != NT * 512 || in_sizes[15] != NT) return;        // fc_w, fc_b
  if (in_sizes[16] != NT || in_sizes[17] != NT) return;              // crf_start, crf_end
  if (in_sizes[18] != NT * NT) return;                               // crf_trans
  if (out_size < SEQ) return;
  if (ws_size < WS_NEEDED_BYTES) return;

  const int*   sent = (const int*)d_in[0];
  const int*   extra = (const int*)d_in[1];
  const float* emb  = (const float*)d_in[4];
  const float* xemb = (const float*)d_in[5];
  const float* wihf = (const float*)d_in[6];
  const float* whhf = (const float*)d_in[7];
  const float* bihf = (const float*)d_in[8];
  const float* bhhf = (const float*)d_in[9];
  const float* wihb = (const float*)d_in[10];
  const float* whhb = (const float*)d_in[11];
  const float* bihb = (const float*)d_in[12];
  const float* bhhb = (const float*)d_in[13];
  const float* fcw  = (const float*)d_in[14];
  const float* fcb  = (const float*)d_in[15];
  const float* cst  = (const float*)d_in[16];
  const float* cen  = (const float*)d_in[17];
  const float* ctr  = (const float*)d_in[18];

  float* ws = (float*)d_ws;
  float* GX = ws + OFF_GX;
  float* H  = ws + OFF_H;
  unsigned long long* SLOT = (unsigned long long*)(ws + OFF_SL);
  float* FE = ws + OFF_FE;
  unsigned char* BP = (unsigned char*)(ws + OFF_BP);

  k_init<<<1, 256, 0, stream>>>(SLOT);
  k_gx<<<dim3(SEQ / 32, G4 / 256, 2), 512, 0, stream>>>(
      sent, extra, emb, xemb, wihf, wihb, bihf, bhhf, bihb, bhhb, GX);
  k_lstm16<<<32, 256, 0, stream>>>(whhf, whhb, GX, H, SLOT);
  k_feats<<<SEQ / 16, 256, 0, stream>>>(H, H + HSTR, fcw, fcb, FE);
  k_viterbi<<<1, 256, 0, stream>>>(FE, cst, cen, ctr, BP, (int*)d_out);
}